// Round 7
// baseline (182.055 us; speedup 1.0000x reference)
//
#include <hip/hip_runtime.h>
#include <math.h>

typedef float  f32x4 __attribute__((ext_vector_type(4)));
typedef double f64x4 __attribute__((ext_vector_type(4)));

#define H      4096
#define E      64
#define TOPK   8
#define TILE_T 32

// Pre-transpose W[e][k] (f32) into the order the main loop consumes:
//   Wb[ ((m*4 + kg)*64 + e)*4 + i ] = W[e][16m + 4kg + i]
__global__ __launch_bounds__(256)
void transpose_w(const float* __restrict__ Wg, float* __restrict__ Wb)
{
  int n = blockIdx.x * 256 + threadIdx.x;    // 64*4096 = 262144
  int e = n >> 12, k = n & 4095;
  float v = Wg[n];
  int m = k >> 4, kg = (k >> 2) & 3, i = k & 3;
  Wb[(((m * 4 + kg) * 64) + e) * 4 + i] = v;
}

// f64-exact router via v_mfma_f64_16x16x4_f64, runtime-probed readout map.
// R7: 4 independent accumulator chains per wave (2 token-tiles x 2
// expert-tiles) to test whether the 53% MfmaUtil ceiling is
// dependency-chain-bound (R6 disproved occupancy). 8 waves/block =
// {expert-half} x {K-quarter}; grid 512 -> 2 blocks/CU, 4 waves/SIMD.
__global__ __launch_bounds__(512, 4)
void moe_gate_mfma(const float* __restrict__ X, const float* __restrict__ Wb,
                   float* __restrict__ out, int n_tokens)
{
  __shared__ double Ls[TILE_T * E];   // 16 KB: f64 partial-sum + epilogue

  const int tid  = threadIdx.x;
  const int lane = tid & 63;
  const int w    = tid >> 6;      // 0..7
  const int wg   = w >> 1;        // K quarter 0..3
  const int we   = w & 1;         // expert half: experts 32we .. 32we+31
  const int t0   = blockIdx.x * TILE_T;
  const int l15  = lane & 15;
  const int kg   = lane >> 4;

  // ---- probe the effective (lane,reg) -> (token,expert) readout map ----
  f64x4 z = {0.0, 0.0, 0.0, 0.0};
  f64x4 pcol = __builtin_amdgcn_mfma_f64_16x16x4f64(1.0, (double)l15, z, 0, 0, 0);
  f64x4 prow = __builtin_amdgcn_mfma_f64_16x16x4f64((double)l15, 1.0, z, 0, 0, 0);
  int qrow[4], qcol[4];
  #pragma unroll
  for (int r = 0; r < 4; ++r) {
    qrow[r] = (int)(prow[r] * 0.25 + 0.5);
    qcol[r] = (int)(pcol[r] * 0.25 + 0.5);
  }

  const int kbase = wg * (H / 4);           // 0,1024,2048,3072
  const int mbase = wg * 64;                // 64 k16-steps per quarter
  const float* xp0 = X  + (size_t)(t0 + l15) * H + kbase + 4 * kg;        // tokens 0..15
  const float* xp1 = X  + (size_t)(t0 + 16 + l15) * H + kbase + 4 * kg;   // tokens 16..31
  const float* bp0 = Wb + (((size_t)mbase * 4 + kg) * 64 + 32 * we + l15) * 4;      // experts 32we+l15
  const float* bp1 = Wb + (((size_t)mbase * 4 + kg) * 64 + 32 * we + 16 + l15) * 4; // experts 32we+16+l15

  f64x4 c00 = {0.0, 0.0, 0.0, 0.0};   // tok-tile0 x exp-tile0
  f64x4 c01 = {0.0, 0.0, 0.0, 0.0};   // tok-tile0 x exp-tile1
  f64x4 c10 = {0.0, 0.0, 0.0, 0.0};   // tok-tile1 x exp-tile0
  f64x4 c11 = {0.0, 0.0, 0.0, 0.0};   // tok-tile1 x exp-tile1

  f32x4 a0 = *(const f32x4*)(xp0);
  f32x4 a1 = *(const f32x4*)(xp1);
  f32x4 b0 = *(const f32x4*)(bp0);
  f32x4 b1 = *(const f32x4*)(bp1);

  #pragma unroll 4
  for (int m = 0; m < 63; ++m) {
    f32x4 na0 = *(const f32x4*)(xp0 + (m + 1) * 16);
    f32x4 na1 = *(const f32x4*)(xp1 + (m + 1) * 16);
    f32x4 nb0 = *(const f32x4*)(bp0 + (size_t)(m + 1) * 1024);
    f32x4 nb1 = *(const f32x4*)(bp1 + (size_t)(m + 1) * 1024);
    #pragma unroll
    for (int i = 0; i < 4; ++i) {
      double a0d = (double)a0[i], a1d = (double)a1[i];
      double b0d = (double)b0[i], b1d = (double)b1[i];
      c00 = __builtin_amdgcn_mfma_f64_16x16x4f64(a0d, b0d, c00, 0, 0, 0);
      c01 = __builtin_amdgcn_mfma_f64_16x16x4f64(a0d, b1d, c01, 0, 0, 0);
      c10 = __builtin_amdgcn_mfma_f64_16x16x4f64(a1d, b0d, c10, 0, 0, 0);
      c11 = __builtin_amdgcn_mfma_f64_16x16x4f64(a1d, b1d, c11, 0, 0, 0);
    }
    a0 = na0; a1 = na1; b0 = nb0; b1 = nb1;
  }
  #pragma unroll
  for (int i = 0; i < 4; ++i) {   // last step of this quarter
    double a0d = (double)a0[i], a1d = (double)a1[i];
    double b0d = (double)b0[i], b1d = (double)b1[i];
    c00 = __builtin_amdgcn_mfma_f64_16x16x4f64(a0d, b0d, c00, 0, 0, 0);
    c01 = __builtin_amdgcn_mfma_f64_16x16x4f64(a0d, b1d, c01, 0, 0, 0);
    c10 = __builtin_amdgcn_mfma_f64_16x16x4f64(a1d, b0d, c10, 0, 0, 0);
    c11 = __builtin_amdgcn_mfma_f64_16x16x4f64(a1d, b1d, c11, 0, 0, 0);
  }

  // ---- combine K-quarters in LDS (wg0 writes, wg1..3 add in turn) ----
  if (wg == 0) {
    #pragma unroll
    for (int r = 0; r < 4; ++r) {
      Ls[qrow[r] * E + 32 * we + qcol[r]]             = c00[r];
      Ls[qrow[r] * E + 32 * we + 16 + qcol[r]]        = c01[r];
      Ls[(16 + qrow[r]) * E + 32 * we + qcol[r]]      = c10[r];
      Ls[(16 + qrow[r]) * E + 32 * we + 16 + qcol[r]] = c11[r];
    }
  }
  __syncthreads();
  #pragma unroll
  for (int g = 1; g < 4; ++g) {
    if (wg == g) {
      #pragma unroll
      for (int r = 0; r < 4; ++r) {
        Ls[qrow[r] * E + 32 * we + qcol[r]]             += c00[r];
        Ls[qrow[r] * E + 32 * we + 16 + qcol[r]]        += c01[r];
        Ls[(16 + qrow[r]) * E + 32 * we + qcol[r]]      += c10[r];
        Ls[(16 + qrow[r]) * E + 32 * we + 16 + qcol[r]] += c11[r];
      }
    }
    __syncthreads();
  }

  // ---- per-token softmax + top-8 on f64 logits (verified R2/R4/R5) ----
  // 8 waves x 4 tokens = 32 tokens
  for (int tt = 0; tt < 4; tt++) {
    int t = w * 4 + tt;
    double val = Ls[t * E + lane];

    double mx = val;
    #pragma unroll
    for (int off = 32; off >= 1; off >>= 1)
      mx = fmax(mx, __shfl_xor(mx, off));

    double p = exp(val - mx);
    double S = p;
    #pragma unroll
    for (int off = 32; off >= 1; off >>= 1)
      S += __shfl_xor(S, off);

    double cur = val;
    double myw = 0.0; int myidx = 0;
    double psum = 0.0;
    #pragma unroll
    for (int r = 0; r < TOPK; r++) {
      double v = cur; int ii = lane;
      #pragma unroll
      for (int off = 32; off >= 1; off >>= 1) {
        double ov = __shfl_xor(v, off);
        int    oi = __shfl_xor(ii, off);
        if (ov > v || (ov == v && oi < ii)) { v = ov; ii = oi; }
      }
      double pw = __shfl(p, ii);
      psum += pw;
      if (lane == r) { myw = pw; myidx = ii; }
      if (lane == ii) cur = -INFINITY;
    }
    double denom = psum / S + 1e-20;
    if (lane < TOPK) {
      size_t gt = (size_t)(t0 + t);
      out[gt * TOPK + lane] = (float)((myw / S) / denom);
      out[(size_t)n_tokens * TOPK + gt * TOPK + lane] = (float)myidx;
    }
  }
}

extern "C" void kernel_launch(void* const* d_in, const int* in_sizes, int n_in,
                              void* d_out, int out_size, void* d_ws, size_t ws_size,
                              hipStream_t stream)
{
  const float* X  = (const float*)d_in[0];
  const float* Wg = (const float*)d_in[1];
  float* out = (float*)d_out;
  float* Wb  = (float*)d_ws;            // 1 MB scratch
  int n_tokens = in_sizes[0] / H;       // 16384

  transpose_w<<<(E * H) / 256, 256, 0, stream>>>(Wg, Wb);
  moe_gate_mfma<<<n_tokens / TILE_T, 512, 0, stream>>>(X, Wb, out, n_tokens);
}